// Round 2
// baseline (999.707 us; speedup 1.0000x reference)
//
#include <hip/hip_runtime.h>
#include <hip/hip_bf16.h>

// Self-attention: context = softmax((X@Wq)(X@Wk)^T / sqrt(d)) @ X
// N=8192, d=1024, fp32. Scores are near-one-hot (score std ~1024 post-scale
// vs top-2 gap ~240) => fp32-grade score accuracy required. f16 split
// (hi+lo, 3-term Ootomo) MFMA GEMMs for projections and QK^T; plain f16
// MFMA for P@V.
//
// ws budget is adaptive (round-0 crashed by assuming 344 MB):
//   persistent 80 MB: XT(16) Qhi(16) Qlo(16) Khi(16) Klo(16)
//   transient  48 MB: Xhi(16) Xlo(16) W-splits(8) -- dead after projections
//   Plan A (ws >= ~212 MB): compact P f16 (128 MB) overlays transient region;
//     S chunks above 208 MB; single full-grid PV GEMM.
//   Plan B (small ws): S chunks overlay transient region at 80 MB; P written
//     f16 in-place into S rows; PV GEMM per chunk.

typedef _Float16 f16x8 __attribute__((ext_vector_type(8)));
typedef float    f32x4 __attribute__((ext_vector_type(4)));

#define TM 128
#define TN 128
#define BK 32                 // k-step in halves
#define LDS_STRIDE (BK + 8)   // pad to de-pattern bank conflicts

// ---------------------------------------------------------------- helpers

// split fp32 -> f16 hi + f16 lo (x ~= hi + lo, residual ~ |x|*2^-22)
__global__ __launch_bounds__(256) void split_rows(const float* __restrict__ src,
                                                  _Float16* __restrict__ hi,
                                                  _Float16* __restrict__ lo,
                                                  long n) {
    long i = (long)blockIdx.x * blockDim.x + threadIdx.x;
    long stride = (long)gridDim.x * blockDim.x;
    for (; i < n; i += stride) {
        float v = src[i];
        _Float16 h = (_Float16)v;
        hi[i] = h;
        lo[i] = (_Float16)(v - (float)h);
    }
}

// dst[c][r] = src[r][c]; optional lo-part output (nullptr => hi only)
__global__ void transpose_split(const float* __restrict__ src,
                                _Float16* __restrict__ dhi,
                                _Float16* __restrict__ dlo,
                                int R, int C) {
    __shared__ float tile[32][33];
    int c0 = blockIdx.x * 32, r0 = blockIdx.y * 32;
    int tx = threadIdx.x, ty = threadIdx.y;   // (32, 8)
#pragma unroll
    for (int k = 0; k < 4; ++k)
        tile[ty + 8 * k][tx] = src[(size_t)(r0 + ty + 8 * k) * C + c0 + tx];
    __syncthreads();
#pragma unroll
    for (int k = 0; k < 4; ++k) {
        float v = tile[tx][ty + 8 * k];
        _Float16 h = (_Float16)v;
        size_t idx = (size_t)(c0 + ty + 8 * k) * R + r0 + tx;
        dhi[idx] = h;
        if (dlo) dlo[idx] = (_Float16)(v - (float)h);
    }
}

// ---------------------------------------------------------------- GEMM
// C[M,N] fp32 = sum_k A[M,K] * B_bt[N,K]^T  (row-major; B in transposed form).
// TERMS==3: A = Ahi+Alo, B = Bhi+Blo, compute hh + hl + lh (Ootomo 3-term).
// SPLIT_OUT==1: epilogue stores f16 hi/lo pair instead of fp32.
template <int TERMS, int SPLIT_OUT>
__global__ __launch_bounds__(256, 2) void gemm_bt(
    const _Float16* __restrict__ Ahi, const _Float16* __restrict__ Alo,
    const _Float16* __restrict__ Bhi, const _Float16* __restrict__ Blo,
    float* __restrict__ C, _Float16* __restrict__ Chi, _Float16* __restrict__ Clo,
    int M, int N, int K, long lda, long ldb, long ldc) {
    __shared__ _Float16 sA[TERMS == 3 ? 2 : 1][TM][LDS_STRIDE];
    __shared__ _Float16 sB[TERMS == 3 ? 2 : 1][TN][LDS_STRIDE];

    const int t = threadIdx.x;
    const int wave = t >> 6;
    const int lane = t & 63;
    const int lm = lane & 15;     // row/col within 16-tile
    const int lq = lane >> 4;     // quad 0..3
    const int wr = wave >> 1;     // wave row 0..1
    const int wc = wave & 1;      // wave col 0..1

    const long rowBase = (long)blockIdx.y * TM;
    const long colBase = (long)blockIdx.x * TN;

    const int lr = t >> 2;          // 0..63 staging row
    const int lg = (t & 3) * 8;     // half offset within BK (16B groups)

    f32x4 acc[4][4];
#pragma unroll
    for (int r = 0; r < 4; ++r)
#pragma unroll
        for (int c = 0; c < 4; ++c)
#pragma unroll
            for (int i = 0; i < 4; ++i) acc[r][c][i] = 0.0f;

    for (int k0 = 0; k0 < K; k0 += BK) {
        __syncthreads();
#pragma unroll
        for (int h = 0; h < 2; ++h) {
            int r = lr + 64 * h;
            *(uint4*)&sA[0][r][lg] =
                *(const uint4*)(Ahi + (rowBase + r) * lda + k0 + lg);
            *(uint4*)&sB[0][r][lg] =
                *(const uint4*)(Bhi + (colBase + r) * ldb + k0 + lg);
            if constexpr (TERMS == 3) {
                *(uint4*)&sA[1][r][lg] =
                    *(const uint4*)(Alo + (rowBase + r) * lda + k0 + lg);
                *(uint4*)&sB[1][r][lg] =
                    *(const uint4*)(Blo + (colBase + r) * ldb + k0 + lg);
            }
        }
        __syncthreads();

        f16x8 ah[4], bh[4], al[4], bl[4];
#pragma unroll
        for (int r = 0; r < 4; ++r) {
            ah[r] = *(const f16x8*)&sA[0][wr * 64 + r * 16 + lm][lq * 8];
            bh[r] = *(const f16x8*)&sB[0][wc * 64 + r * 16 + lm][lq * 8];
            if constexpr (TERMS == 3) {
                al[r] = *(const f16x8*)&sA[1][wr * 64 + r * 16 + lm][lq * 8];
                bl[r] = *(const f16x8*)&sB[1][wc * 64 + r * 16 + lm][lq * 8];
            }
        }
#pragma unroll
        for (int r = 0; r < 4; ++r)
#pragma unroll
            for (int c = 0; c < 4; ++c) {
                acc[r][c] = __builtin_amdgcn_mfma_f32_16x16x32_f16(
                    ah[r], bh[c], acc[r][c], 0, 0, 0);
                if constexpr (TERMS == 3) {
                    acc[r][c] = __builtin_amdgcn_mfma_f32_16x16x32_f16(
                        ah[r], bl[c], acc[r][c], 0, 0, 0);
                    acc[r][c] = __builtin_amdgcn_mfma_f32_16x16x32_f16(
                        al[r], bh[c], acc[r][c], 0, 0, 0);
                }
            }
    }

    // C/D layout: col = lane&15, row = quad*4 + reg  (verified m89/m91)
#pragma unroll
    for (int r = 0; r < 4; ++r)
#pragma unroll
        for (int c = 0; c < 4; ++c)
#pragma unroll
            for (int i = 0; i < 4; ++i) {
                long row = rowBase + wr * 64 + r * 16 + lq * 4 + i;
                long col = colBase + wc * 64 + c * 16 + lm;
                if constexpr (SPLIT_OUT) {
                    float v = acc[r][c][i];
                    _Float16 h = (_Float16)v;
                    Chi[row * ldc + col] = h;
                    Clo[row * ldc + col] = (_Float16)(v - (float)h);
                } else {
                    C[row * ldc + col] = acc[r][c][i];
                }
            }
}

// ---------------------------------------------------------------- softmax
// One block per row (8192 fp32). Reads the whole row into registers, reduces
// max and sum(exp), writes P f16 to prow (may alias the fp32 row in-place:
// all reads complete before the first barrier, writes after the last).
// Scale 1/32 (= 1/sqrt(1024), exact pow2) folded in.
__global__ __launch_bounds__(256) void softmax_rows(const float* __restrict__ S,
                                                    _Float16* __restrict__ P,
                                                    long ldp, int N) {
    const int row = blockIdx.x;
    const int t = threadIdx.x;
    const float* rowp = S + (size_t)row * N;
    float vals[32];
    float mx = -3.4e38f;
#pragma unroll
    for (int i = 0; i < 32; ++i) {
        vals[i] = rowp[t + 256 * i];
        mx = fmaxf(mx, vals[i]);
    }
    __shared__ float red[8];
#pragma unroll
    for (int off = 32; off >= 1; off >>= 1) mx = fmaxf(mx, __shfl_xor(mx, off));
    if ((t & 63) == 0) red[t >> 6] = mx;
    __syncthreads();
    mx = fmaxf(fmaxf(red[0], red[1]), fmaxf(red[2], red[3]));

    float sum = 0.0f;
#pragma unroll
    for (int i = 0; i < 32; ++i) {
        float p = __expf((vals[i] - mx) * 0.03125f);
        vals[i] = p;
        sum += p;
    }
#pragma unroll
    for (int off = 32; off >= 1; off >>= 1) sum += __shfl_xor(sum, off);
    if ((t & 63) == 0) red[4 + (t >> 6)] = sum;
    __syncthreads();
    float inv = 1.0f / (red[4] + red[5] + red[6] + red[7]);

    _Float16* prow = P + (size_t)row * ldp;
#pragma unroll
    for (int i = 0; i < 32; ++i) prow[t + 256 * i] = (_Float16)(vals[i] * inv);
}

// ---------------------------------------------------------------- launch
extern "C" void kernel_launch(void* const* d_in, const int* in_sizes, int n_in,
                              void* d_out, int out_size, void* d_ws, size_t ws_size,
                              hipStream_t stream) {
    const float* X  = (const float*)d_in[0];  // [8192,1024]
    const float* Wq = (const float*)d_in[1];  // [1024,1024]
    const float* Wk = (const float*)d_in[2];  // [1024,1024]
    float* out = (float*)d_out;               // [8192,1024]

    const long Nt = 8192, D = 1024;
    char* ws = (char*)d_ws;
    const size_t MB = 1024ull * 1024ull;

    // Persistent region (80 MB):
    _Float16* XT  = (_Float16*)(ws + 0);        // 16 MB [1024][8192] = X^T f16
    _Float16* Qhi = (_Float16*)(ws + 16 * MB);  // 16 MB
    _Float16* Qlo = (_Float16*)(ws + 32 * MB);
    _Float16* Khi = (_Float16*)(ws + 48 * MB);
    _Float16* Klo = (_Float16*)(ws + 64 * MB);
    // Transient (dead after projections):
    _Float16* Xhi   = (_Float16*)(ws + 80 * MB);   // 16 MB
    _Float16* Xlo   = (_Float16*)(ws + 96 * MB);   // 16 MB
    _Float16* WqThi = (_Float16*)(ws + 112 * MB);  // 2 MB each
    _Float16* WqTlo = (_Float16*)(ws + 114 * MB);
    _Float16* WkThi = (_Float16*)(ws + 116 * MB);
    _Float16* WkTlo = (_Float16*)(ws + 118 * MB);

    const size_t rowBytes = (size_t)Nt * 4;  // 32 KB per S row
    const bool planA = ws_size >= 208 * MB + 128 * rowBytes;
    _Float16* Pbuf = (_Float16*)(ws + 80 * MB);   // plan A: 128 MB compact P
    float* Sc;
    long chunk;
    if (planA) {
        Sc = (float*)(ws + 208 * MB);
        size_t avail = ws_size - 208 * MB;
        chunk = (long)((avail / rowBytes / 128) * 128);
    } else {
        Sc = (float*)(ws + 80 * MB);
        size_t avail = ws_size > 80 * MB ? ws_size - 80 * MB : 0;
        chunk = (long)((avail / rowBytes / 128) * 128);
        if (chunk < 128) chunk = 128;  // last resort; smaller ws cannot work
    }
    if (chunk > Nt) chunk = Nt;

    // 1. prep: transpose X (f16 V^T), split X, transpose+split weights
    transpose_split<<<dim3(32, 256), dim3(32, 8), 0, stream>>>(X, XT, nullptr,
                                                               (int)Nt, (int)D);
    split_rows<<<1024, 256, 0, stream>>>(X, Xhi, Xlo, Nt * D);
    transpose_split<<<dim3(32, 32), dim3(32, 8), 0, stream>>>(Wq, WqThi, WqTlo,
                                                              (int)D, (int)D);
    transpose_split<<<dim3(32, 32), dim3(32, 8), 0, stream>>>(Wk, WkThi, WkTlo,
                                                              (int)D, (int)D);

    // 2. projections (3-term split), epilogue splits straight to f16 hi/lo
    gemm_bt<3, 1><<<dim3(D / TN, Nt / TM), 256, 0, stream>>>(
        Xhi, Xlo, WqThi, WqTlo, nullptr, Qhi, Qlo,
        (int)Nt, (int)D, (int)D, D, D, D);
    gemm_bt<3, 1><<<dim3(D / TN, Nt / TM), 256, 0, stream>>>(
        Xhi, Xlo, WkThi, WkTlo, nullptr, Khi, Klo,
        (int)Nt, (int)D, (int)D, D, D, D);

    // 3. chunks: S = Q@K^T (3-term, fp32), softmax -> P f16
    long done = 0;
    while (done < Nt) {
        long cur = Nt - done < chunk ? Nt - done : chunk;
        gemm_bt<3, 0><<<dim3(Nt / TN, cur / TM), 256, 0, stream>>>(
            Qhi + done * D, Qlo + done * D, Khi, Klo, Sc, nullptr, nullptr,
            (int)cur, (int)Nt, (int)D, D, D, Nt);
        if (planA) {
            softmax_rows<<<(int)cur, 256, 0, stream>>>(Sc, Pbuf + done * Nt,
                                                       Nt, (int)Nt);
        } else {
            softmax_rows<<<(int)cur, 256, 0, stream>>>(Sc, (_Float16*)Sc,
                                                       2 * Nt, (int)Nt);
            gemm_bt<1, 0><<<dim3(D / TN, cur / TM), 256, 0, stream>>>(
                (const _Float16*)Sc, nullptr, XT, nullptr,
                out + done * D, nullptr, nullptr,
                (int)cur, (int)D, (int)Nt, 2 * Nt, Nt, D);
        }
        done += cur;
    }

    // 4. plan A: one full-grid PV GEMM: context = P @ X (B = X^T)
    if (planA) {
        gemm_bt<1, 0><<<dim3(D / TN, Nt / TM), 256, 0, stream>>>(
            Pbuf, nullptr, XT, nullptr, out, nullptr, nullptr,
            (int)Nt, (int)D, (int)Nt, Nt, Nt, D);
    }
}

// Round 3
// 899.568 us; speedup vs baseline: 1.1113x; 1.1113x over previous
//
#include <hip/hip_runtime.h>
#include <hip/hip_bf16.h>

// Self-attention: context = softmax((X@Wq)(X@Wk)^T / sqrt(d)) @ X
// N=8192, d=1024, fp32. Near-one-hot scores => fp32-grade score accuracy:
// f16 split (hi+lo, 3-term Ootomo) MFMA GEMMs for projections and QK^T;
// plain f16 MFMA for P@V.
//
// R3: m97-style staging (global_load_lds width-16, unpadded 64B LDS rows)
//     + XCD-aware grid orientation (SWAP=1 for PV/proj: grid.x=row-blocks,
//     so the 8 col-blocks sharing an A-tile land on one XCD's L2).

typedef _Float16 f16x8 __attribute__((ext_vector_type(8)));
typedef _Float16 f16x4 __attribute__((ext_vector_type(4)));
typedef float    f32x4 __attribute__((ext_vector_type(4)));

#define TM 128
#define TN 128
#define BK 32   // k-step in halves; 32 halves = 64 B LDS row (unpadded)

// async global->LDS, 16 B per lane; LDS dest = wave-uniform base + lane*16
__device__ __forceinline__ void g2lds16(const _Float16* g, _Float16* l) {
    __builtin_amdgcn_global_load_lds(
        (__attribute__((address_space(1))) unsigned int*)(g),
        (__attribute__((address_space(3))) unsigned int*)(l),
        16, 0, 0);
}

// ---------------------------------------------------------------- helpers

// split fp32 -> f16 hi + f16 lo (x ~= hi + lo, residual ~ |x|*2^-22)
__global__ __launch_bounds__(256) void split_rows(const float* __restrict__ src,
                                                  _Float16* __restrict__ hi,
                                                  _Float16* __restrict__ lo,
                                                  long n) {
    long i = (long)blockIdx.x * blockDim.x + threadIdx.x;
    long stride = (long)gridDim.x * blockDim.x;
    for (; i < n; i += stride) {
        float v = src[i];
        _Float16 h = (_Float16)v;
        hi[i] = h;
        lo[i] = (_Float16)(v - (float)h);
    }
}

// dst[c][r] = src[r][c]; optional lo-part output (nullptr => hi only)
__global__ void transpose_split(const float* __restrict__ src,
                                _Float16* __restrict__ dhi,
                                _Float16* __restrict__ dlo,
                                int R, int C) {
    __shared__ float tile[32][33];
    int c0 = blockIdx.x * 32, r0 = blockIdx.y * 32;
    int tx = threadIdx.x, ty = threadIdx.y;   // (32, 8)
#pragma unroll
    for (int k = 0; k < 4; ++k)
        tile[ty + 8 * k][tx] = src[(size_t)(r0 + ty + 8 * k) * C + c0 + tx];
    __syncthreads();
#pragma unroll
    for (int k = 0; k < 4; ++k) {
        float v = tile[tx][ty + 8 * k];
        _Float16 h = (_Float16)v;
        size_t idx = (size_t)(c0 + ty + 8 * k) * R + r0 + tx;
        dhi[idx] = h;
        if (dlo) dlo[idx] = (_Float16)(v - (float)h);
    }
}

// ---------------------------------------------------------------- GEMM
// C[M,N] fp32 = sum_k A[M,K] * B_bt[N,K]^T  (row-major; B in transposed form).
// TERMS==3: A = Ahi+Alo, B = Bhi+Blo, compute hh + hl + lh (Ootomo 3-term).
// SPLIT_OUT==1: epilogue stores f16 hi/lo pair instead of fp32.
// SWAP==1: blockIdx.x indexes row-blocks (use when A-reuse across col-blocks
//   should be XCD-co-located: grid.x multiple of 8 => id%8 == rowblk%8).
template <int TERMS, int SPLIT_OUT, int SWAP>
__global__ __launch_bounds__(256, 2) void gemm_bt(
    const _Float16* __restrict__ Ahi, const _Float16* __restrict__ Alo,
    const _Float16* __restrict__ Bhi, const _Float16* __restrict__ Blo,
    float* __restrict__ C, _Float16* __restrict__ Chi, _Float16* __restrict__ Clo,
    long lda, long ldb, long ldc, int K) {
    constexpr int NBUF = (TERMS == 3) ? 4 : 2;     // hi/lo x A/B  or  A/B
    __shared__ __align__(16) _Float16 s[NBUF * 128 * BK];

    const int t = threadIdx.x;
    const int wave = t >> 6;
    const int lane = t & 63;
    const int lm = lane & 15;     // row/col within 16-tile
    const int lq = lane >> 4;     // quad 0..3
    const int wr = wave >> 1;     // wave row 0..1
    const int wc = wave & 1;      // wave col 0..1

    const long rowBase = (long)(SWAP ? blockIdx.x : blockIdx.y) * TM;
    const long colBase = (long)(SWAP ? blockIdx.y : blockIdx.x) * TN;

    // --- staging assignment (per wave) ---
    const _Float16* src;
    long myLd, gRow0;
    int ldsBaseH;
    if constexpr (TERMS == 3) {
        // wave 0: Ahi  1: Alo  2: Bhi  3: Blo ; each 128 rows = 8 issues
        const _Float16* a = (wave & 1) ? Alo : Ahi;
        const _Float16* b = (wave & 1) ? Blo : Bhi;
        src = (wave & 2) ? b : a;
        myLd = (wave & 2) ? ldb : lda;
        gRow0 = (wave & 2) ? colBase : rowBase;
        ldsBaseH = wave * (128 * BK);
    } else {
        // wave 0: A rows 0-63  1: A rows 64-127  2: B 0-63  3: B 64-127
        src = (wave & 2) ? Bhi : Ahi;
        myLd = (wave & 2) ? ldb : lda;
        gRow0 = ((wave & 2) ? colBase : rowBase) + (wave & 1) * 64;
        ldsBaseH = (wave >> 1) * (128 * BK) + (wave & 1) * (64 * BK);
    }
    constexpr int NISS = (TERMS == 3) ? 8 : 4;  // 16 rows (1 KB) per issue
    const _Float16* rp = src + (gRow0 + (lane >> 2)) * myLd + (lane & 3) * 8;
    _Float16* ldsW = &s[ldsBaseH];

    const _Float16* sAh = s;
    const _Float16* sBh = s + (TERMS == 3 ? 2 : 1) * 128 * BK;
    const _Float16* sAl = s + 128 * BK;       // TERMS==3 only
    const _Float16* sBl = s + 3 * 128 * BK;   // TERMS==3 only

    f32x4 acc[4][4];
#pragma unroll
    for (int r = 0; r < 4; ++r)
#pragma unroll
        for (int c = 0; c < 4; ++c)
#pragma unroll
            for (int i = 0; i < 4; ++i) acc[r][c][i] = 0.0f;

    for (int k0 = 0; k0 < K; k0 += BK) {
        __syncthreads();   // LDS safe to overwrite
#pragma unroll
        for (int j = 0; j < NISS; ++j)
            g2lds16(rp + (long)(j * 16) * myLd + k0, ldsW + j * 512);
        __syncthreads();   // drains vmcnt before barrier => data visible

        f16x8 ah[4], bh[4], al[4], bl[4];
#pragma unroll
        for (int r = 0; r < 4; ++r) {
            int ra = (wr * 64 + r * 16 + lm) * BK + lq * 8;
            int rb = (wc * 64 + r * 16 + lm) * BK + lq * 8;
            ah[r] = *(const f16x8*)&sAh[ra];
            bh[r] = *(const f16x8*)&sBh[rb];
            if constexpr (TERMS == 3) {
                al[r] = *(const f16x8*)&sAl[ra];
                bl[r] = *(const f16x8*)&sBl[rb];
            }
        }
#pragma unroll
        for (int r = 0; r < 4; ++r)
#pragma unroll
            for (int c = 0; c < 4; ++c) {
                acc[r][c] = __builtin_amdgcn_mfma_f32_16x16x32_f16(
                    ah[r], bh[c], acc[r][c], 0, 0, 0);
                if constexpr (TERMS == 3) {
                    acc[r][c] = __builtin_amdgcn_mfma_f32_16x16x32_f16(
                        ah[r], bl[c], acc[r][c], 0, 0, 0);
                    acc[r][c] = __builtin_amdgcn_mfma_f32_16x16x32_f16(
                        al[r], bh[c], acc[r][c], 0, 0, 0);
                }
            }
    }

    // C/D layout: col = lane&15, row = quad*4 + reg  (verified m89/m91)
#pragma unroll
    for (int r = 0; r < 4; ++r)
#pragma unroll
        for (int c = 0; c < 4; ++c)
#pragma unroll
            for (int i = 0; i < 4; ++i) {
                long row = rowBase + wr * 64 + r * 16 + lq * 4 + i;
                long col = colBase + wc * 64 + c * 16 + lm;
                if constexpr (SPLIT_OUT) {
                    float v = acc[r][c][i];
                    _Float16 h = (_Float16)v;
                    Chi[row * ldc + col] = h;
                    Clo[row * ldc + col] = (_Float16)(v - (float)h);
                } else {
                    C[row * ldc + col] = acc[r][c][i];
                }
            }
}

// ---------------------------------------------------------------- softmax
// One block per row (8192 fp32). Whole row into registers (float4), reduce
// max and sum(exp), write P f16 (may alias the fp32 row in-place: all reads
// complete before first barrier, writes after last). Scale 1/32 folded in.
__global__ __launch_bounds__(256) void softmax_rows(const float* __restrict__ S,
                                                    _Float16* __restrict__ P,
                                                    long ldp, int N) {
    const int row = blockIdx.x;
    const int t = threadIdx.x;
    const float4* rowp = (const float4*)(S + (size_t)row * N);
    float4 v[8];
    float mx = -3.4e38f;
#pragma unroll
    for (int i = 0; i < 8; ++i) {
        v[i] = rowp[t + 256 * i];
        mx = fmaxf(mx, fmaxf(fmaxf(v[i].x, v[i].y), fmaxf(v[i].z, v[i].w)));
    }
    __shared__ float red[8];
#pragma unroll
    for (int off = 32; off >= 1; off >>= 1) mx = fmaxf(mx, __shfl_xor(mx, off));
    if ((t & 63) == 0) red[t >> 6] = mx;
    __syncthreads();
    mx = fmaxf(fmaxf(red[0], red[1]), fmaxf(red[2], red[3]));

    float sum = 0.0f;
#pragma unroll
    for (int i = 0; i < 8; ++i) {
        v[i].x = __expf((v[i].x - mx) * 0.03125f);
        v[i].y = __expf((v[i].y - mx) * 0.03125f);
        v[i].z = __expf((v[i].z - mx) * 0.03125f);
        v[i].w = __expf((v[i].w - mx) * 0.03125f);
        sum += (v[i].x + v[i].y) + (v[i].z + v[i].w);
    }
#pragma unroll
    for (int off = 32; off >= 1; off >>= 1) sum += __shfl_xor(sum, off);
    if ((t & 63) == 0) red[4 + (t >> 6)] = sum;
    __syncthreads();
    float inv = 1.0f / (red[4] + red[5] + red[6] + red[7]);

    f16x4* prow = (f16x4*)(P + (size_t)row * ldp);
#pragma unroll
    for (int i = 0; i < 8; ++i) {
        f16x4 o;
        o[0] = (_Float16)(v[i].x * inv);
        o[1] = (_Float16)(v[i].y * inv);
        o[2] = (_Float16)(v[i].z * inv);
        o[3] = (_Float16)(v[i].w * inv);
        prow[t + 256 * i] = o;
    }
}

// ---------------------------------------------------------------- launch
extern "C" void kernel_launch(void* const* d_in, const int* in_sizes, int n_in,
                              void* d_out, int out_size, void* d_ws, size_t ws_size,
                              hipStream_t stream) {
    const float* X  = (const float*)d_in[0];  // [8192,1024]
    const float* Wq = (const float*)d_in[1];  // [1024,1024]
    const float* Wk = (const float*)d_in[2];  // [1024,1024]
    float* out = (float*)d_out;               // [8192,1024]

    const long Nt = 8192, D = 1024;
    char* ws = (char*)d_ws;
    const size_t MB = 1024ull * 1024ull;

    // Persistent region (80 MB):
    _Float16* XT  = (_Float16*)(ws + 0);        // 16 MB [1024][8192] = X^T f16
    _Float16* Qhi = (_Float16*)(ws + 16 * MB);  // 16 MB
    _Float16* Qlo = (_Float16*)(ws + 32 * MB);
    _Float16* Khi = (_Float16*)(ws + 48 * MB);
    _Float16* Klo = (_Float16*)(ws + 64 * MB);
    // Transient (dead after projections):
    _Float16* Xhi   = (_Float16*)(ws + 80 * MB);   // 16 MB
    _Float16* Xlo   = (_Float16*)(ws + 96 * MB);   // 16 MB
    _Float16* WqThi = (_Float16*)(ws + 112 * MB);  // 2 MB each
    _Float16* WqTlo = (_Float16*)(ws + 114 * MB);
    _Float16* WkThi = (_Float16*)(ws + 116 * MB);
    _Float16* WkTlo = (_Float16*)(ws + 118 * MB);

    const size_t rowBytes = (size_t)Nt * 4;  // 32 KB per S row
    const bool planA = ws_size >= 208 * MB + 128 * rowBytes;
    _Float16* Pbuf = (_Float16*)(ws + 80 * MB);   // plan A: 128 MB compact P
    float* Sc;
    long chunk;
    if (planA) {
        Sc = (float*)(ws + 208 * MB);
        size_t avail = ws_size - 208 * MB;
        chunk = (long)((avail / rowBytes / 128) * 128);
    } else {
        Sc = (float*)(ws + 80 * MB);
        size_t avail = ws_size > 80 * MB ? ws_size - 80 * MB : 0;
        chunk = (long)((avail / rowBytes / 128) * 128);
        if (chunk < 128) chunk = 128;  // last resort; smaller ws cannot work
    }
    if (chunk > Nt) chunk = Nt;

    // 1. prep: transpose X (f16 V^T), split X, transpose+split weights
    transpose_split<<<dim3(32, 256), dim3(32, 8), 0, stream>>>(X, XT, nullptr,
                                                               (int)Nt, (int)D);
    split_rows<<<1024, 256, 0, stream>>>(X, Xhi, Xlo, Nt * D);
    transpose_split<<<dim3(32, 32), dim3(32, 8), 0, stream>>>(Wq, WqThi, WqTlo,
                                                              (int)D, (int)D);
    transpose_split<<<dim3(32, 32), dim3(32, 8), 0, stream>>>(Wk, WkThi, WkTlo,
                                                              (int)D, (int)D);

    // 2. projections (3-term split), epilogue splits straight to f16 hi/lo.
    //    SWAP=1: grid.x = 64 row-blocks (A-tile co-located per XCD).
    gemm_bt<3, 1, 1><<<dim3(Nt / TM, D / TN), 256, 0, stream>>>(
        Xhi, Xlo, WqThi, WqTlo, nullptr, Qhi, Qlo, D, D, D, (int)D);
    gemm_bt<3, 1, 1><<<dim3(Nt / TM, D / TN), 256, 0, stream>>>(
        Xhi, Xlo, WkThi, WkTlo, nullptr, Khi, Klo, D, D, D, (int)D);

    // 3. chunks: S = Q@K^T (3-term, fp32), softmax -> P f16.
    //    SWAP=0: grid.x = 64 col-blocks (B = K-splits, 32 MB, co-located).
    long done = 0;
    while (done < Nt) {
        long cur = Nt - done < chunk ? Nt - done : chunk;
        gemm_bt<3, 0, 0><<<dim3(Nt / TN, cur / TM), 256, 0, stream>>>(
            Qhi + done * D, Qlo + done * D, Khi, Klo, Sc, nullptr, nullptr,
            D, D, Nt, (int)D);
        if (planA) {
            softmax_rows<<<(int)cur, 256, 0, stream>>>(Sc, Pbuf + done * Nt,
                                                       Nt, (int)Nt);
        } else {
            softmax_rows<<<(int)cur, 256, 0, stream>>>(Sc, (_Float16*)Sc,
                                                       2 * Nt, (int)Nt);
            gemm_bt<1, 0, 1><<<dim3(cur / TM, D / TN), 256, 0, stream>>>(
                (const _Float16*)Sc, nullptr, XT, nullptr,
                out + done * D, nullptr, nullptr, 2 * Nt, Nt, D, (int)Nt);
        }
        done += cur;
    }

    // 4. plan A: one full-grid PV GEMM: context = P @ X (B = X^T).
    //    SWAP=1: grid.x = 64 row-blocks => 8 col-blocks sharing each 2 MB
    //    P-tile land on one XCD (id%8 == rowblk%8) -> A fetched ~once.
    if (planA) {
        gemm_bt<1, 0, 1><<<dim3(Nt / TM, D / TN), 256, 0, stream>>>(
            Pbuf, nullptr, XT, nullptr, out, nullptr, nullptr,
            Nt, Nt, D, (int)Nt);
    }
}

// Round 5
// 886.668 us; speedup vs baseline: 1.1275x; 1.0145x over previous
//
#include <hip/hip_runtime.h>
#include <hip/hip_bf16.h>

// Self-attention: context = softmax((X@Wq)(X@Wk)^T / sqrt(d)) @ X
// N=8192, d=1024, fp32. Near-one-hot scores => fp32-grade score accuracy:
// f16 split (hi+lo, 3-term Ootomo) MFMA GEMMs for projections and QK^T;
// plain f16 MFMA for P@V.
//
// R5: fix R4's fused-projection zB offset (WqThi->WkThi is 4 MB = 2M halves,
//     not 1M; the 1M bug made K = X@(Wq_lo + Wk_hi) -> argmax flips).
//     Keeps R4's occupancy push: PV split-K=2 (1024 blocks, 4/CU),
//     launch_bounds 3 (TERMS=3) / 4 (TERMS=1) blocks/CU, fused Q+K proj.

typedef _Float16 f16x8 __attribute__((ext_vector_type(8)));
typedef _Float16 f16x4 __attribute__((ext_vector_type(4)));
typedef float    f32x4 __attribute__((ext_vector_type(4)));

#define TM 128
#define TN 128
#define BK 32   // k-step in halves; 32 halves = 64 B LDS row (unpadded)

// async global->LDS, 16 B per lane; LDS dest = wave-uniform base + lane*16
__device__ __forceinline__ void g2lds16(const _Float16* g, _Float16* l) {
    __builtin_amdgcn_global_load_lds(
        (__attribute__((address_space(1))) unsigned int*)(g),
        (__attribute__((address_space(3))) unsigned int*)(l),
        16, 0, 0);
}

// ---------------------------------------------------------------- helpers

// split fp32 -> f16 hi + f16 lo (x ~= hi + lo, residual ~ |x|*2^-22)
__global__ __launch_bounds__(256) void split_rows(const float* __restrict__ src,
                                                  _Float16* __restrict__ hi,
                                                  _Float16* __restrict__ lo,
                                                  long n) {
    long i = (long)blockIdx.x * blockDim.x + threadIdx.x;
    long stride = (long)gridDim.x * blockDim.x;
    for (; i < n; i += stride) {
        float v = src[i];
        _Float16 h = (_Float16)v;
        hi[i] = h;
        lo[i] = (_Float16)(v - (float)h);
    }
}

// dst[c][r] = src[r][c]; optional lo-part output (nullptr => hi only)
__global__ void transpose_split(const float* __restrict__ src,
                                _Float16* __restrict__ dhi,
                                _Float16* __restrict__ dlo,
                                int R, int C) {
    __shared__ float tile[32][33];
    int c0 = blockIdx.x * 32, r0 = blockIdx.y * 32;
    int tx = threadIdx.x, ty = threadIdx.y;   // (32, 8)
#pragma unroll
    for (int k = 0; k < 4; ++k)
        tile[ty + 8 * k][tx] = src[(size_t)(r0 + ty + 8 * k) * C + c0 + tx];
    __syncthreads();
#pragma unroll
    for (int k = 0; k < 4; ++k) {
        float v = tile[tx][ty + 8 * k];
        _Float16 h = (_Float16)v;
        size_t idx = (size_t)(c0 + ty + 8 * k) * R + r0 + tx;
        dhi[idx] = h;
        if (dlo) dlo[idx] = (_Float16)(v - (float)h);
    }
}

// out = a + b (final split-K reduction), float4 grid-stride
__global__ __launch_bounds__(256) void add_rows(const float* __restrict__ a,
                                                const float* __restrict__ b,
                                                float* __restrict__ out, long n4) {
    long i = (long)blockIdx.x * blockDim.x + threadIdx.x;
    long stride = (long)gridDim.x * blockDim.x;
    for (; i < n4; i += stride) {
        float4 x = ((const float4*)a)[i];
        float4 y = ((const float4*)b)[i];
        x.x += y.x; x.y += y.y; x.z += y.z; x.w += y.w;
        ((float4*)out)[i] = x;
    }
}

// ---------------------------------------------------------------- GEMM
// C[M,N] fp32 = sum_k A[M,K] * B_bt[N,K]^T  (row-major; B in transposed form).
// TERMS==3: A = Ahi+Alo, B = Bhi+Blo, compute hh + hl + lh (Ootomo 3-term).
// SPLIT_OUT==1: epilogue stores f16 hi/lo pair instead of fp32.
// SWAP==1: blockIdx.x indexes row-blocks (A-reuse XCD-co-located).
// gridDim.z slices: pointer offsets zA/zB/zC (elements) per blockIdx.z —
//   used for fused Q/K projections (zB,zC) and PV split-K (zA,zB,zC).
template <int TERMS, int SPLIT_OUT, int SWAP>
__global__ __launch_bounds__(256, TERMS == 3 ? 3 : 4) void gemm_bt(
    const _Float16* __restrict__ Ahi, const _Float16* __restrict__ Alo,
    const _Float16* __restrict__ Bhi, const _Float16* __restrict__ Blo,
    float* __restrict__ C, _Float16* __restrict__ Chi, _Float16* __restrict__ Clo,
    long lda, long ldb, long ldc, int K, long zA, long zB, long zC) {
    constexpr int NBUF = (TERMS == 3) ? 4 : 2;     // hi/lo x A/B  or  A/B
    __shared__ __align__(16) _Float16 s[NBUF * 128 * BK];

    const long z = blockIdx.z;
    Ahi += z * zA;
    Bhi += z * zB;
    if constexpr (TERMS == 3) { Alo += z * zA; Blo += z * zB; }
    if constexpr (SPLIT_OUT) { Chi += z * zC; Clo += z * zC; }
    else C += z * zC;

    const int t = threadIdx.x;
    const int wave = t >> 6;
    const int lane = t & 63;
    const int lm = lane & 15;     // row/col within 16-tile
    const int lq = lane >> 4;     // quad 0..3
    const int wr = wave >> 1;     // wave row 0..1
    const int wc = wave & 1;      // wave col 0..1

    const long rowBase = (long)(SWAP ? blockIdx.x : blockIdx.y) * TM;
    const long colBase = (long)(SWAP ? blockIdx.y : blockIdx.x) * TN;

    // --- staging assignment (per wave) ---
    const _Float16* src;
    long myLd, gRow0;
    int ldsBaseH;
    if constexpr (TERMS == 3) {
        // wave 0: Ahi  1: Alo  2: Bhi  3: Blo ; each 128 rows = 8 issues
        const _Float16* a = (wave & 1) ? Alo : Ahi;
        const _Float16* b = (wave & 1) ? Blo : Bhi;
        src = (wave & 2) ? b : a;
        myLd = (wave & 2) ? ldb : lda;
        gRow0 = (wave & 2) ? colBase : rowBase;
        ldsBaseH = wave * (128 * BK);
    } else {
        // wave 0: A rows 0-63  1: A rows 64-127  2: B 0-63  3: B 64-127
        src = (wave & 2) ? Bhi : Ahi;
        myLd = (wave & 2) ? ldb : lda;
        gRow0 = ((wave & 2) ? colBase : rowBase) + (wave & 1) * 64;
        ldsBaseH = (wave >> 1) * (128 * BK) + (wave & 1) * (64 * BK);
    }
    constexpr int NISS = (TERMS == 3) ? 8 : 4;  // 16 rows (1 KB) per issue
    const _Float16* rp = src + (gRow0 + (lane >> 2)) * myLd + (lane & 3) * 8;
    _Float16* ldsW = &s[ldsBaseH];

    const _Float16* sAh = s;
    const _Float16* sBh = s + (TERMS == 3 ? 2 : 1) * 128 * BK;
    const _Float16* sAl = s + 128 * BK;       // TERMS==3 only
    const _Float16* sBl = s + 3 * 128 * BK;   // TERMS==3 only

    f32x4 acc[4][4];
#pragma unroll
    for (int r = 0; r < 4; ++r)
#pragma unroll
        for (int c = 0; c < 4; ++c)
#pragma unroll
            for (int i = 0; i < 4; ++i) acc[r][c][i] = 0.0f;

    for (int k0 = 0; k0 < K; k0 += BK) {
        __syncthreads();   // LDS safe to overwrite
#pragma unroll
        for (int j = 0; j < NISS; ++j)
            g2lds16(rp + (long)(j * 16) * myLd + k0, ldsW + j * 512);
        __syncthreads();   // drains vmcnt before barrier => data visible

        f16x8 ah[4], bh[4], al[4], bl[4];
#pragma unroll
        for (int r = 0; r < 4; ++r) {
            int ra = (wr * 64 + r * 16 + lm) * BK + lq * 8;
            int rb = (wc * 64 + r * 16 + lm) * BK + lq * 8;
            ah[r] = *(const f16x8*)&sAh[ra];
            bh[r] = *(const f16x8*)&sBh[rb];
            if constexpr (TERMS == 3) {
                al[r] = *(const f16x8*)&sAl[ra];
                bl[r] = *(const f16x8*)&sBl[rb];
            }
        }
#pragma unroll
        for (int r = 0; r < 4; ++r)
#pragma unroll
            for (int c = 0; c < 4; ++c) {
                acc[r][c] = __builtin_amdgcn_mfma_f32_16x16x32_f16(
                    ah[r], bh[c], acc[r][c], 0, 0, 0);
                if constexpr (TERMS == 3) {
                    acc[r][c] = __builtin_amdgcn_mfma_f32_16x16x32_f16(
                        ah[r], bl[c], acc[r][c], 0, 0, 0);
                    acc[r][c] = __builtin_amdgcn_mfma_f32_16x16x32_f16(
                        al[r], bh[c], acc[r][c], 0, 0, 0);
                }
            }
    }

    // C/D layout: col = lane&15, row = quad*4 + reg  (verified m89/m91)
#pragma unroll
    for (int r = 0; r < 4; ++r)
#pragma unroll
        for (int c = 0; c < 4; ++c)
#pragma unroll
            for (int i = 0; i < 4; ++i) {
                long row = rowBase + wr * 64 + r * 16 + lq * 4 + i;
                long col = colBase + wc * 64 + c * 16 + lm;
                if constexpr (SPLIT_OUT) {
                    float v = acc[r][c][i];
                    _Float16 h = (_Float16)v;
                    Chi[row * ldc + col] = h;
                    Clo[row * ldc + col] = (_Float16)(v - (float)h);
                } else {
                    C[row * ldc + col] = acc[r][c][i];
                }
            }
}

// ---------------------------------------------------------------- softmax
// One block per row (8192 fp32). Whole row into registers (float4), reduce
// max and sum(exp), write P f16 (may alias the fp32 row in-place: all reads
// complete before first barrier, writes after last). Scale 1/32 folded in.
__global__ __launch_bounds__(256) void softmax_rows(const float* __restrict__ S,
                                                    _Float16* __restrict__ P,
                                                    long ldp, int N) {
    const int row = blockIdx.x;
    const int t = threadIdx.x;
    const float4* rowp = (const float4*)(S + (size_t)row * N);
    float4 v[8];
    float mx = -3.4e38f;
#pragma unroll
    for (int i = 0; i < 8; ++i) {
        v[i] = rowp[t + 256 * i];
        mx = fmaxf(mx, fmaxf(fmaxf(v[i].x, v[i].y), fmaxf(v[i].z, v[i].w)));
    }
    __shared__ float red[8];
#pragma unroll
    for (int off = 32; off >= 1; off >>= 1) mx = fmaxf(mx, __shfl_xor(mx, off));
    if ((t & 63) == 0) red[t >> 6] = mx;
    __syncthreads();
    mx = fmaxf(fmaxf(red[0], red[1]), fmaxf(red[2], red[3]));

    float sum = 0.0f;
#pragma unroll
    for (int i = 0; i < 8; ++i) {
        v[i].x = __expf((v[i].x - mx) * 0.03125f);
        v[i].y = __expf((v[i].y - mx) * 0.03125f);
        v[i].z = __expf((v[i].z - mx) * 0.03125f);
        v[i].w = __expf((v[i].w - mx) * 0.03125f);
        sum += (v[i].x + v[i].y) + (v[i].z + v[i].w);
    }
#pragma unroll
    for (int off = 32; off >= 1; off >>= 1) sum += __shfl_xor(sum, off);
    if ((t & 63) == 0) red[4 + (t >> 6)] = sum;
    __syncthreads();
    float inv = 1.0f / (red[4] + red[5] + red[6] + red[7]);

    f16x4* prow = (f16x4*)(P + (size_t)row * ldp);
#pragma unroll
    for (int i = 0; i < 8; ++i) {
        f16x4 o;
        o[0] = (_Float16)(v[i].x * inv);
        o[1] = (_Float16)(v[i].y * inv);
        o[2] = (_Float16)(v[i].z * inv);
        o[3] = (_Float16)(v[i].w * inv);
        prow[t + 256 * i] = o;
    }
}

// ---------------------------------------------------------------- launch
extern "C" void kernel_launch(void* const* d_in, const int* in_sizes, int n_in,
                              void* d_out, int out_size, void* d_ws, size_t ws_size,
                              hipStream_t stream) {
    const float* X  = (const float*)d_in[0];  // [8192,1024]
    const float* Wq = (const float*)d_in[1];  // [1024,1024]
    const float* Wk = (const float*)d_in[2];  // [1024,1024]
    float* out = (float*)d_out;               // [8192,1024]

    const long Nt = 8192, D = 1024;
    char* ws = (char*)d_ws;
    const size_t MB = 1024ull * 1024ull;

    // Persistent region (80 MB):
    _Float16* XT  = (_Float16*)(ws + 0);        // 16 MB [1024][8192] = X^T f16
    _Float16* Qhi = (_Float16*)(ws + 16 * MB);  // 16 MB   (dead after S-GEMMs;
    _Float16* Qlo = (_Float16*)(ws + 32 * MB);  //          reused as PK0/PK1)
    _Float16* Khi = (_Float16*)(ws + 48 * MB);
    _Float16* Klo = (_Float16*)(ws + 64 * MB);
    // Transient (dead after projections):
    _Float16* Xhi   = (_Float16*)(ws + 80 * MB);   // 16 MB
    _Float16* Xlo   = (_Float16*)(ws + 96 * MB);   // 16 MB
    _Float16* WqThi = (_Float16*)(ws + 112 * MB);  // 2 MB each, Wq/Wk adjacent
    _Float16* WqTlo = (_Float16*)(ws + 114 * MB);
    _Float16* WkThi = (_Float16*)(ws + 116 * MB);
    _Float16* WkTlo = (_Float16*)(ws + 118 * MB);
    // PV split-K partials (alias dead Qhi..Klo): 2 x 32 MB fp32
    float* PK0 = (float*)(ws + 16 * MB);

    const size_t rowBytes = (size_t)Nt * 4;  // 32 KB per S row
    const bool planA = ws_size >= 208 * MB + 128 * rowBytes;
    _Float16* Pbuf = (_Float16*)(ws + 80 * MB);   // plan A: 128 MB compact P
    float* Sc;
    long chunk;
    if (planA) {
        Sc = (float*)(ws + 208 * MB);
        size_t avail = ws_size - 208 * MB;
        chunk = (long)((avail / rowBytes / 128) * 128);
    } else {
        Sc = (float*)(ws + 80 * MB);
        size_t avail = ws_size > 80 * MB ? ws_size - 80 * MB : 0;
        chunk = (long)((avail / rowBytes / 128) * 128);
        if (chunk < 128) chunk = 128;  // last resort; smaller ws cannot work
    }
    if (chunk > Nt) chunk = Nt;

    // 1. prep: transpose X (f16 V^T), split X, transpose+split weights
    transpose_split<<<dim3(32, 256), dim3(32, 8), 0, stream>>>(X, XT, nullptr,
                                                               (int)Nt, (int)D);
    split_rows<<<1024, 256, 0, stream>>>(X, Xhi, Xlo, Nt * D);
    transpose_split<<<dim3(32, 32), dim3(32, 8), 0, stream>>>(Wq, WqThi, WqTlo,
                                                              (int)D, (int)D);
    transpose_split<<<dim3(32, 32), dim3(32, 8), 0, stream>>>(Wk, WkThi, WkTlo,
                                                              (int)D, (int)D);

    // 2. fused Q+K projections (3-term split), z=0 -> Q, z=1 -> K.
    //    zB = WkThi-WqThi = 4 MB = 2M halves (hi AND lo shift together:
    //    WqTlo+2M = WkTlo). zC = Khi-Qhi = 32 MB = 16M halves (Qlo->Klo ok).
    //    SWAP=1: id%8 = row-block%8 for both z => X tiles XCD-co-located.
    gemm_bt<3, 1, 1><<<dim3(Nt / TM, D / TN, 2), 256, 0, stream>>>(
        Xhi, Xlo, WqThi, WqTlo, nullptr, Qhi, Qlo, D, D, D, (int)D,
        0, (long)(4 * MB / 2), (long)(32 * MB / 2));

    // 3. chunks: S = Q@K^T (3-term, fp32), softmax -> P f16.
    //    SWAP=0: grid.x = 64 col-blocks (B = K-splits, 32 MB, co-located).
    long done = 0;
    while (done < Nt) {
        long cur = Nt - done < chunk ? Nt - done : chunk;
        gemm_bt<3, 0, 0><<<dim3(Nt / TN, cur / TM, 1), 256, 0, stream>>>(
            Qhi + done * D, Qlo + done * D, Khi, Klo, Sc, nullptr, nullptr,
            D, D, Nt, (int)D, 0, 0, 0);
        if (planA) {
            softmax_rows<<<(int)cur, 256, 0, stream>>>(Sc, Pbuf + done * Nt,
                                                       Nt, (int)Nt);
        } else {
            softmax_rows<<<(int)cur, 256, 0, stream>>>(Sc, (_Float16*)Sc,
                                                       2 * Nt, (int)Nt);
            gemm_bt<1, 0, 1><<<dim3(cur / TM, D / TN, 1), 256, 0, stream>>>(
                (const _Float16*)Sc, nullptr, XT, nullptr,
                out + done * D, nullptr, nullptr, 2 * Nt, Nt, D, (int)Nt,
                0, 0, 0);
        }
        done += cur;
    }

    // 4. plan A: PV split-K=2 (z slices K halves; partials PK0/PK1 in the
    //    dead Q/K region), then reduce. 1024 blocks -> 4/CU.
    if (planA) {
        gemm_bt<1, 0, 1><<<dim3(Nt / TM, D / TN, 2), 256, 0, stream>>>(
            Pbuf, nullptr, XT, nullptr, PK0, nullptr, nullptr,
            Nt, Nt, D, (int)(Nt / 2),
            Nt / 2, Nt / 2, Nt * D);
        add_rows<<<1024, 256, 0, stream>>>(PK0, PK0 + Nt * D, out, Nt * D / 4);
    }
}

// Round 6
// 856.086 us; speedup vs baseline: 1.1678x; 1.0357x over previous
//
#include <hip/hip_runtime.h>
#include <hip/hip_bf16.h>

// Self-attention: context = softmax((X@Wq)(X@Wk)^T / sqrt(d)) @ X
// N=8192, d=1024, fp32. Near-one-hot scores => fp32-grade score accuracy:
// f16 split (hi+lo, 3-term Ootomo) MFMA GEMMs for projections and QK^T;
// plain f16 MFMA for P@V.
//
// R6: (a) XOR-swizzled LDS columns (SQ_LDS_BANK_CONFLICT was 15% of PV
//     cycles; unpadded rows alias 8-way). global_load_lds forces LDS dest
//     = base + lane*16, so the swizzle is applied to the GLOBAL column per
//     lane: LDS[row][slot] = global[row][slot ^ swz(row)]; reader XORs the
//     same. BK=32: swz=(row>>1)&3; BK=64: swz=row&7 -> 2-way (free).
//     (b) PV BK=64: 32 MFMA/barrier (was 16; TERMS=3 at 48 runs ~966 TF vs
//     PV's 743), LDS still 32 KB, 4 blocks/CU. (c) even-size S chunks.

typedef _Float16 f16x8 __attribute__((ext_vector_type(8)));
typedef _Float16 f16x4 __attribute__((ext_vector_type(4)));
typedef float    f32x4 __attribute__((ext_vector_type(4)));

#define TM 128
#define TN 128

// async global->LDS, 16 B per lane; LDS dest = wave-uniform base + lane*16
__device__ __forceinline__ void g2lds16(const _Float16* g, _Float16* l) {
    __builtin_amdgcn_global_load_lds(
        (__attribute__((address_space(1))) unsigned int*)(g),
        (__attribute__((address_space(3))) unsigned int*)(l),
        16, 0, 0);
}

// ---------------------------------------------------------------- helpers

// split fp32 -> f16 hi + f16 lo (x ~= hi + lo, residual ~ |x|*2^-22)
__global__ __launch_bounds__(256) void split_rows(const float* __restrict__ src,
                                                  _Float16* __restrict__ hi,
                                                  _Float16* __restrict__ lo,
                                                  long n) {
    long i = (long)blockIdx.x * blockDim.x + threadIdx.x;
    long stride = (long)gridDim.x * blockDim.x;
    for (; i < n; i += stride) {
        float v = src[i];
        _Float16 h = (_Float16)v;
        hi[i] = h;
        lo[i] = (_Float16)(v - (float)h);
    }
}

// dst[c][r] = src[r][c]; optional lo-part output (nullptr => hi only)
__global__ void transpose_split(const float* __restrict__ src,
                                _Float16* __restrict__ dhi,
                                _Float16* __restrict__ dlo,
                                int R, int C) {
    __shared__ float tile[32][33];
    int c0 = blockIdx.x * 32, r0 = blockIdx.y * 32;
    int tx = threadIdx.x, ty = threadIdx.y;   // (32, 8)
#pragma unroll
    for (int k = 0; k < 4; ++k)
        tile[ty + 8 * k][tx] = src[(size_t)(r0 + ty + 8 * k) * C + c0 + tx];
    __syncthreads();
#pragma unroll
    for (int k = 0; k < 4; ++k) {
        float v = tile[tx][ty + 8 * k];
        _Float16 h = (_Float16)v;
        size_t idx = (size_t)(c0 + ty + 8 * k) * R + r0 + tx;
        dhi[idx] = h;
        if (dlo) dlo[idx] = (_Float16)(v - (float)h);
    }
}

// out = a + b (final split-K reduction), float4 grid-stride
__global__ __launch_bounds__(256) void add_rows(const float* __restrict__ a,
                                                const float* __restrict__ b,
                                                float* __restrict__ out, long n4) {
    long i = (long)blockIdx.x * blockDim.x + threadIdx.x;
    long stride = (long)gridDim.x * blockDim.x;
    for (; i < n4; i += stride) {
        float4 x = ((const float4*)a)[i];
        float4 y = ((const float4*)b)[i];
        x.x += y.x; x.y += y.y; x.z += y.z; x.w += y.w;
        ((float4*)out)[i] = x;
    }
}

// ---------------------------------------------------------------- GEMM
// C[M,N] fp32 = sum_k A[M,K] * B_bt[N,K]^T  (row-major; B in transposed form).
// TERMS==3: A = Ahi+Alo, B = Bhi+Blo, compute hh + hl + lh (Ootomo 3-term).
// SPLIT_OUT==1: epilogue stores f16 hi/lo pair instead of fp32.
// SWAP==1: blockIdx.x indexes row-blocks (A-reuse XCD-co-located).
// BKH: k-step in halves (32 or 64); LDS row = BKH halves, XOR-swizzled.
// gridDim.z slices via element offsets zA/zB/zC (fused proj / split-K PV).
template <int TERMS, int SPLIT_OUT, int SWAP, int BKH>
__global__ __launch_bounds__(256, TERMS == 3 ? 3 : 4) void gemm_bt(
    const _Float16* __restrict__ Ahi, const _Float16* __restrict__ Alo,
    const _Float16* __restrict__ Bhi, const _Float16* __restrict__ Blo,
    float* __restrict__ C, _Float16* __restrict__ Chi, _Float16* __restrict__ Clo,
    long lda, long ldb, long ldc, int K, long zA, long zB, long zC) {
    constexpr int NBUF = (TERMS == 3) ? 4 : 2;     // hi/lo x A/B  or  A/B
    __shared__ __align__(16) _Float16 s[NBUF * 128 * BKH];

    const long z = blockIdx.z;
    Ahi += z * zA;
    Bhi += z * zB;
    if constexpr (TERMS == 3) { Alo += z * zA; Blo += z * zB; }
    if constexpr (SPLIT_OUT) { Chi += z * zC; Clo += z * zC; }
    else C += z * zC;

    const int t = threadIdx.x;
    const int wave = t >> 6;
    const int lane = t & 63;
    const int lm = lane & 15;     // row/col within 16-tile
    const int lq = lane >> 4;     // quad 0..3
    const int wr = wave >> 1;     // wave row 0..1
    const int wc = wave & 1;      // wave col 0..1

    const long rowBase = (long)(SWAP ? blockIdx.x : blockIdx.y) * TM;
    const long colBase = (long)(SWAP ? blockIdx.y : blockIdx.x) * TN;

    // --- staging assignment (per wave) ---
    const _Float16* src;
    long myLd, gRow0;
    int ldsBaseH;
    if constexpr (TERMS == 3) {
        // wave 0: Ahi  1: Alo  2: Bhi  3: Blo ; 128 rows each
        const _Float16* a = (wave & 1) ? Alo : Ahi;
        const _Float16* b = (wave & 1) ? Blo : Bhi;
        src = (wave & 2) ? b : a;
        myLd = (wave & 2) ? ldb : lda;
        gRow0 = (wave & 2) ? colBase : rowBase;
        ldsBaseH = wave * (128 * BKH);
    } else {
        // wave 0: A rows 0-63  1: A rows 64-127  2: B 0-63  3: B 64-127
        src = (wave & 2) ? Bhi : Ahi;
        myLd = (wave & 2) ? ldb : lda;
        gRow0 = ((wave & 2) ? colBase : rowBase) + (wave & 1) * 64;
        ldsBaseH = (wave >> 1) * (128 * BKH) + (wave & 1) * (64 * BKH);
    }
    // lanes per row / rows per 1KB issue; 8 issues cover the wave's rows.
    constexpr int LPR = BKH / 8;          // 4 (BKH=32) or 8 (BKH=64)
    constexpr int RPI = 64 / LPR;         // 16 or 8
    constexpr int NISS = (TERMS == 3 ? 128 : 64) / RPI;   // 8 both ways
    const int lr = lane / LPR;            // row within issue
    const int slot = lane % LPR;          // 16B column slot
    // XOR swizzle: LDS[row][slot] holds global col group slot^swz(row).
    // issues stride RPI rows, so row mod RPI is lane-invariant across j.
    const int swzW = (BKH == 32) ? ((lr >> 1) & 3) : (lr & 7);
    const _Float16* rp = src + (gRow0 + lr) * myLd + (slot ^ swzW) * 8;
    _Float16* ldsW = &s[ldsBaseH];

    const _Float16* sAh = s;
    const _Float16* sBh = s + (TERMS == 3 ? 2 : 1) * 128 * BKH;
    const _Float16* sAl = s + 128 * BKH;       // TERMS==3 only
    const _Float16* sBl = s + 3 * 128 * BKH;   // TERMS==3 only

    // reader-side swizzle (row = ..64/16-aligned base + lm)
    const int swzR = (BKH == 32) ? ((lm >> 1) & 3) : (lm & 7);

    f32x4 acc[4][4];
#pragma unroll
    for (int r = 0; r < 4; ++r)
#pragma unroll
        for (int c = 0; c < 4; ++c)
#pragma unroll
            for (int i = 0; i < 4; ++i) acc[r][c][i] = 0.0f;

    for (int k0 = 0; k0 < K; k0 += BKH) {
        __syncthreads();   // LDS safe to overwrite
#pragma unroll
        for (int j = 0; j < NISS; ++j)
            g2lds16(rp + (long)(j * RPI) * myLd + k0, ldsW + j * 512);
        __syncthreads();   // drains vmcnt before barrier => data visible

#pragma unroll
        for (int kk = 0; kk < BKH; kk += 32) {
            const int gb = kk >> 3;   // column-group base (8 halves/group)
            f16x8 ah[4], bh[4], al[4], bl[4];
#pragma unroll
            for (int r = 0; r < 4; ++r) {
                int ra = (wr * 64 + r * 16 + lm) * BKH + ((gb + lq) ^ swzR) * 8;
                int rb = (wc * 64 + r * 16 + lm) * BKH + ((gb + lq) ^ swzR) * 8;
                ah[r] = *(const f16x8*)&sAh[ra];
                bh[r] = *(const f16x8*)&sBh[rb];
                if constexpr (TERMS == 3) {
                    al[r] = *(const f16x8*)&sAl[ra];
                    bl[r] = *(const f16x8*)&sBl[rb];
                }
            }
#pragma unroll
            for (int r = 0; r < 4; ++r)
#pragma unroll
                for (int c = 0; c < 4; ++c) {
                    acc[r][c] = __builtin_amdgcn_mfma_f32_16x16x32_f16(
                        ah[r], bh[c], acc[r][c], 0, 0, 0);
                    if constexpr (TERMS == 3) {
                        acc[r][c] = __builtin_amdgcn_mfma_f32_16x16x32_f16(
                            ah[r], bl[c], acc[r][c], 0, 0, 0);
                        acc[r][c] = __builtin_amdgcn_mfma_f32_16x16x32_f16(
                            al[r], bh[c], acc[r][c], 0, 0, 0);
                    }
                }
        }
    }

    // C/D layout: col = lane&15, row = quad*4 + reg  (verified m89/m91)
#pragma unroll
    for (int r = 0; r < 4; ++r)
#pragma unroll
        for (int c = 0; c < 4; ++c)
#pragma unroll
            for (int i = 0; i < 4; ++i) {
                long row = rowBase + wr * 64 + r * 16 + lq * 4 + i;
                long col = colBase + wc * 64 + c * 16 + lm;
                if constexpr (SPLIT_OUT) {
                    float v = acc[r][c][i];
                    _Float16 h = (_Float16)v;
                    Chi[row * ldc + col] = h;
                    Clo[row * ldc + col] = (_Float16)(v - (float)h);
                } else {
                    C[row * ldc + col] = acc[r][c][i];
                }
            }
}

// ---------------------------------------------------------------- softmax
// One block per row (8192 fp32). Whole row into registers (float4), reduce
// max and sum(exp), write P f16 (may alias the fp32 row in-place: all reads
// complete before first barrier, writes after last). Scale 1/32 folded in.
__global__ __launch_bounds__(256) void softmax_rows(const float* __restrict__ S,
                                                    _Float16* __restrict__ P,
                                                    long ldp, int N) {
    const int row = blockIdx.x;
    const int t = threadIdx.x;
    const float4* rowp = (const float4*)(S + (size_t)row * N);
    float4 v[8];
    float mx = -3.4e38f;
#pragma unroll
    for (int i = 0; i < 8; ++i) {
        v[i] = rowp[t + 256 * i];
        mx = fmaxf(mx, fmaxf(fmaxf(v[i].x, v[i].y), fmaxf(v[i].z, v[i].w)));
    }
    __shared__ float red[8];
#pragma unroll
    for (int off = 32; off >= 1; off >>= 1) mx = fmaxf(mx, __shfl_xor(mx, off));
    if ((t & 63) == 0) red[t >> 6] = mx;
    __syncthreads();
    mx = fmaxf(fmaxf(red[0], red[1]), fmaxf(red[2], red[3]));

    float sum = 0.0f;
#pragma unroll
    for (int i = 0; i < 8; ++i) {
        v[i].x = __expf((v[i].x - mx) * 0.03125f);
        v[i].y = __expf((v[i].y - mx) * 0.03125f);
        v[i].z = __expf((v[i].z - mx) * 0.03125f);
        v[i].w = __expf((v[i].w - mx) * 0.03125f);
        sum += (v[i].x + v[i].y) + (v[i].z + v[i].w);
    }
#pragma unroll
    for (int off = 32; off >= 1; off >>= 1) sum += __shfl_xor(sum, off);
    if ((t & 63) == 0) red[4 + (t >> 6)] = sum;
    __syncthreads();
    float inv = 1.0f / (red[4] + red[5] + red[6] + red[7]);

    f16x4* prow = (f16x4*)(P + (size_t)row * ldp);
#pragma unroll
    for (int i = 0; i < 8; ++i) {
        f16x4 o;
        o[0] = (_Float16)(v[i].x * inv);
        o[1] = (_Float16)(v[i].y * inv);
        o[2] = (_Float16)(v[i].z * inv);
        o[3] = (_Float16)(v[i].w * inv);
        prow[t + 256 * i] = o;
    }
}

// ---------------------------------------------------------------- launch
extern "C" void kernel_launch(void* const* d_in, const int* in_sizes, int n_in,
                              void* d_out, int out_size, void* d_ws, size_t ws_size,
                              hipStream_t stream) {
    const float* X  = (const float*)d_in[0];  // [8192,1024]
    const float* Wq = (const float*)d_in[1];  // [1024,1024]
    const float* Wk = (const float*)d_in[2];  // [1024,1024]
    float* out = (float*)d_out;               // [8192,1024]

    const long Nt = 8192, D = 1024;
    char* ws = (char*)d_ws;
    const size_t MB = 1024ull * 1024ull;

    // Persistent region (80 MB):
    _Float16* XT  = (_Float16*)(ws + 0);        // 16 MB [1024][8192] = X^T f16
    _Float16* Qhi = (_Float16*)(ws + 16 * MB);  // 16 MB   (dead after S-GEMMs;
    _Float16* Qlo = (_Float16*)(ws + 32 * MB);  //          reused as PK0/PK1)
    _Float16* Khi = (_Float16*)(ws + 48 * MB);
    _Float16* Klo = (_Float16*)(ws + 64 * MB);
    // Transient (dead after projections):
    _Float16* Xhi   = (_Float16*)(ws + 80 * MB);   // 16 MB
    _Float16* Xlo   = (_Float16*)(ws + 96 * MB);   // 16 MB
    _Float16* WqThi = (_Float16*)(ws + 112 * MB);  // 2 MB each, Wq/Wk adjacent
    _Float16* WqTlo = (_Float16*)(ws + 114 * MB);
    _Float16* WkThi = (_Float16*)(ws + 116 * MB);
    _Float16* WkTlo = (_Float16*)(ws + 118 * MB);
    // PV split-K partials (alias dead Qhi..Klo): 2 x 32 MB fp32
    float* PK0 = (float*)(ws + 16 * MB);

    const size_t rowBytes = (size_t)Nt * 4;  // 32 KB per S row
    const bool planA = ws_size >= 208 * MB + 128 * rowBytes;
    _Float16* Pbuf = (_Float16*)(ws + 80 * MB);   // plan A: 128 MB compact P
    float* Sc;
    long chunk;
    if (planA) {
        Sc = (float*)(ws + 208 * MB);
        size_t avail = ws_size - 208 * MB;
        chunk = (long)((avail / rowBytes / 128) * 128);
    } else {
        Sc = (float*)(ws + 80 * MB);
        size_t avail = ws_size > 80 * MB ? ws_size - 80 * MB : 0;
        chunk = (long)((avail / rowBytes / 128) * 128);
        if (chunk < 128) chunk = 128;  // last resort; smaller ws cannot work
    }
    if (chunk > Nt) chunk = Nt;
    // even-size chunks (avoid a tiny low-occupancy tail chunk)
    {
        long nch = (Nt + chunk - 1) / chunk;
        chunk = (((Nt + nch - 1) / nch) + 127) / 128 * 128;
    }

    // 1. prep: transpose X (f16 V^T), split X, transpose+split weights
    transpose_split<<<dim3(32, 256), dim3(32, 8), 0, stream>>>(X, XT, nullptr,
                                                               (int)Nt, (int)D);
    split_rows<<<1024, 256, 0, stream>>>(X, Xhi, Xlo, Nt * D);
    transpose_split<<<dim3(32, 32), dim3(32, 8), 0, stream>>>(Wq, WqThi, WqTlo,
                                                              (int)D, (int)D);
    transpose_split<<<dim3(32, 32), dim3(32, 8), 0, stream>>>(Wk, WkThi, WkTlo,
                                                              (int)D, (int)D);

    // 2. fused Q+K projections (3-term split), z=0 -> Q, z=1 -> K.
    //    zB = WkThi-WqThi = 4 MB = 2M halves; zC = Khi-Qhi = 16M halves.
    gemm_bt<3, 1, 1, 32><<<dim3(Nt / TM, D / TN, 2), 256, 0, stream>>>(
        Xhi, Xlo, WqThi, WqTlo, nullptr, Qhi, Qlo, D, D, D, (int)D,
        0, (long)(4 * MB / 2), (long)(32 * MB / 2));

    // 3. chunks: S = Q@K^T (3-term, fp32), softmax -> P f16.
    //    SWAP=0: grid.x = 64 col-blocks (B = K-splits, 32 MB, co-located).
    long done = 0;
    while (done < Nt) {
        long cur = Nt - done < chunk ? Nt - done : chunk;
        gemm_bt<3, 0, 0, 32><<<dim3(Nt / TN, cur / TM, 1), 256, 0, stream>>>(
            Qhi + done * D, Qlo + done * D, Khi, Klo, Sc, nullptr, nullptr,
            D, D, Nt, (int)D, 0, 0, 0);
        if (planA) {
            softmax_rows<<<(int)cur, 256, 0, stream>>>(Sc, Pbuf + done * Nt,
                                                       Nt, (int)Nt);
        } else {
            softmax_rows<<<(int)cur, 256, 0, stream>>>(Sc, (_Float16*)Sc,
                                                       2 * Nt, (int)Nt);
            gemm_bt<1, 0, 1, 64><<<dim3(cur / TM, D / TN, 1), 256, 0, stream>>>(
                (const _Float16*)Sc, nullptr, XT, nullptr,
                out + done * D, nullptr, nullptr, 2 * Nt, Nt, D, (int)Nt,
                0, 0, 0);
        }
        done += cur;
    }

    // 4. plan A: PV split-K=2, BK=64 (32 MFMA/barrier), partials in the
    //    dead Q/K region, then reduce. 1024 blocks -> 4/CU.
    if (planA) {
        gemm_bt<1, 0, 1, 64><<<dim3(Nt / TM, D / TN, 2), 256, 0, stream>>>(
            Pbuf, nullptr, XT, nullptr, PK0, nullptr, nullptr,
            Nt, Nt, D, (int)(Nt / 2),
            Nt / 2, Nt / 2, Nt * D);
        add_rows<<<1024, 256, 0, stream>>>(PK0, PK0 + Nt * D, out, Nt * D / 4);
    }
}